// Round 19
// baseline (273.850 us; speedup 1.0000x reference)
//
#include <hip/hip_runtime.h>
#include <hip/hip_bf16.h>

typedef __bf16 bf16x8 __attribute__((ext_vector_type(8)));
typedef float f32x4 __attribute__((ext_vector_type(4)));
typedef unsigned short u16x8 __attribute__((ext_vector_type(8)));

#define GLDS16(g, s)                                                         \
  __builtin_amdgcn_global_load_lds(                                          \
      (const __attribute__((address_space(1))) void*)(g),                    \
      (__attribute__((address_space(3))) void*)(s), 16, 0, 0)

__device__ __forceinline__ void store1(__hip_bfloat16* p, float v) { *p = __float2bfloat16(v); }
__device__ __forceinline__ void store1(float* p, float v) { *p = v; }

// ---------------- cast fp32 -> bf16 ----------------
__global__ __launch_bounds__(256) void cast_f32_to_bf16(const float4* __restrict__ in,
                                                        ushort4* __restrict__ out, int n4) {
  int i = blockIdx.x * 256 + threadIdx.x;
  if (i >= n4) return;
  float4 v = in[i];
  union { ushort4 u; __hip_bfloat16 h[4]; } o;
  o.h[0] = __float2bfloat16(v.x);
  o.h[1] = __float2bfloat16(v.y);
  o.h[2] = __float2bfloat16(v.z);
  o.h[3] = __float2bfloat16(v.w);
  out[i] = o.u;
}

// merged 4-weight cast (blockIdx.y selects matrix)
__global__ __launch_bounds__(256) void cast4_f32_to_bf16(const float4* __restrict__ w0,
                                                         const float4* __restrict__ w1,
                                                         const float4* __restrict__ w2,
                                                         const float4* __restrict__ w3,
                                                         ushort4* __restrict__ o0,
                                                         ushort4* __restrict__ o1,
                                                         ushort4* __restrict__ o2,
                                                         ushort4* __restrict__ o3, int n4) {
  int i = blockIdx.x * 256 + threadIdx.x;
  if (i >= n4) return;
  int s = blockIdx.y;
  const float4* in = (s == 0) ? w0 : (s == 1) ? w1 : (s == 2) ? w2 : w3;
  ushort4* out = (s == 0) ? o0 : (s == 1) ? o1 : (s == 2) ? o2 : o3;
  float4 v = in[i];
  union { ushort4 u; __hip_bfloat16 h[4]; } o;
  o.h[0] = __float2bfloat16(v.x);
  o.h[1] = __float2bfloat16(v.y);
  o.h[2] = __float2bfloat16(v.z);
  o.h[3] = __float2bfloat16(v.w);
  out[i] = o.u;
}

// ------- QKV GEMM: 128x256, BK=32, DOUBLE-buf 48 KB -> 3 blocks/CU -------
// Depth-1: per tile {vmcnt(0) [loads issued 1 K-tile earlier]; barrier; read
// 8 b128; stage T(t+1) (3 glds); 64 MFMA}. r17's triple-buf/depth-2 at 72 KB
// capped residency at 2 blocks/CU; depth was never binding (r13/r14: depth-1
// vs depth-2 neutral), TLP is — 48 KB unlocks the 3rd resident block.
// Same 64B-row swizzle as r17: phys slot = logical ^ ((row>>1)&3).
__global__ __launch_bounds__(512, 2) void gemm_qkv(const __hip_bfloat16* __restrict__ A,
                                                   const __hip_bfloat16* __restrict__ B0,
                                                   const __hip_bfloat16* __restrict__ B1,
                                                   const __hip_bfloat16* __restrict__ B2,
                                                   __hip_bfloat16* __restrict__ C0,
                                                   __hip_bfloat16* __restrict__ C1,
                                                   __hip_bfloat16* __restrict__ C2,
                                                   int nBx, int nBy, int ntPerMat,
                                                   int N, int K) {
  __shared__ __hip_bfloat16 As[2][128 * 32];  // 8 KB each
  __shared__ __hip_bfloat16 Bs[2][256 * 32];  // 16 KB each

  const int t = threadIdx.x;
  const int w = t >> 6, l = t & 63;
  const int lr = l & 15, hi = l >> 4;

  const int nwg = nBx * nBy;
  int id = (int)blockIdx.x;
  id = (id & 7) * (nwg >> 3) + (id >> 3);
  const int bx = id / nBy;
  const int by = id % nBy;

  const int sel = bx / ntPerMat;
  const __hip_bfloat16* Bm = (sel == 0) ? B0 : ((sel == 1) ? B1 : B2);
  __hip_bfloat16* Cm = (sel == 0) ? C0 : ((sel == 1) ? C1 : C2);
  const int n0 = (bx - sel * ntPerMat) * 256;
  const int m0 = by * 128;

  const int ar = t >> 2, as_ = t & 3;
  const int swsrc = (as_ ^ ((ar >> 1) & 3)) * 8;
  const __hip_bfloat16* aP  = A  + (size_t)(m0 + ar) * K + swsrc;
  const __hip_bfloat16* bPa = Bm + (size_t)(n0 + ar) * K + swsrc;
  const __hip_bfloat16* bPb = Bm + (size_t)(n0 + 128 + ar) * K + swsrc;

#define STAGE_T(bb, koff)                                                    \
  do {                                                                       \
    GLDS16(aP + (koff), (char*)As[bb] + t * 16);                             \
    GLDS16(bPa + (koff), (char*)Bs[bb] + t * 16);                            \
    GLDS16(bPb + (koff), (char*)Bs[bb] + 8192 + t * 16);                     \
  } while (0)

  f32x4 acc[2][4][2] = {};
  bf16x8 af[4];
  bf16x8 bq[2][2];
  const int NT = K / 32;
  const int swr = (lr >> 1) & 3;
  const int arow = (w >> 2) * 64;
  const int brow = (w & 3) * 32;

#define WAITV(n)  asm volatile("s_waitcnt vmcnt(" #n ")" ::: "memory")

  STAGE_T(0, 0);

  for (int tt = 0; tt < NT; ++tt) {
    const int buf = tt & 1, nb = buf ^ 1;
    const bool stg = (tt + 1 < NT);

    WAITV(0);
    __builtin_amdgcn_s_barrier();

#pragma unroll
    for (int mi = 0; mi < 4; ++mi)
      af[mi] = *(const bf16x8*)((const char*)As[buf] +
          (arow + mi * 16 + lr) * 64 + ((hi ^ swr) << 4));
#pragma unroll
    for (int nh = 0; nh < 2; ++nh)
#pragma unroll
      for (int ni = 0; ni < 2; ++ni)
        bq[nh][ni] = *(const bf16x8*)((const char*)Bs[buf] +
            (nh * 128 + brow + ni * 16 + lr) * 64 + ((hi ^ swr) << 4));

    if (stg) STAGE_T(nb, (size_t)(tt + 1) * 32);

    __builtin_amdgcn_s_setprio(1);
#pragma unroll
    for (int nh = 0; nh < 2; ++nh)
#pragma unroll
      for (int mi = 0; mi < 4; ++mi)
#pragma unroll
        for (int ni = 0; ni < 2; ++ni)
          acc[nh][mi][ni] = __builtin_amdgcn_mfma_f32_16x16x32_bf16(
              af[mi], bq[nh][ni], acc[nh][mi][ni], 0, 0, 0);
    __builtin_amdgcn_s_setprio(0);
  }
#undef WAITV
#undef STAGE_T

#pragma unroll
  for (int nh = 0; nh < 2; ++nh)
#pragma unroll
    for (int mi = 0; mi < 4; ++mi)
#pragma unroll
      for (int ni = 0; ni < 2; ++ni)
#pragma unroll
        for (int i = 0; i < 4; ++i) {
          size_t idx = (size_t)(m0 + arow + mi * 16 + hi * 4 + i) * N +
                       (n0 + nh * 128 + brow + ni * 16 + lr);
          store1(&Cm[idx], acc[nh][mi][ni][i]);
        }
}

// ------- out-proj GEMM: 128x256, BK=64, dbuf single-phase (r15 best: ~19us warm) -------
template <typename OutT>
__global__ __launch_bounds__(512, 2) void gemm_op(const __hip_bfloat16* __restrict__ A,
                                                  const __hip_bfloat16* __restrict__ B0,
                                                  OutT* __restrict__ C0,
                                                  int nBx, int nBy, int N, int K) {
  __shared__ __hip_bfloat16 As[2][128 * 64];  // 16 KB per buf
  __shared__ __hip_bfloat16 Bs[2][256 * 64];  // 32 KB per buf

  const int t = threadIdx.x;
  const int w = t >> 6, l = t & 63;
  const int lr = l & 15, hi = l >> 4;

  const int nwg = nBx * nBy;
  int id = (int)blockIdx.x;
  id = (id & 7) * (nwg >> 3) + (id >> 3);
  const int bx = id / nBy;
  const int by = id % nBy;

  const int n0 = bx * 256;
  const int m0 = by * 128;

  const int c0r = t >> 3, cs = t & 7;
  const int c1r = 64 + c0r;
  const __hip_bfloat16* aP0 = A + (size_t)(m0 + c0r) * K + (cs ^ (c0r & 7)) * 8;
  const __hip_bfloat16* aP1 = A + (size_t)(m0 + c1r) * K + (cs ^ (c1r & 7)) * 8;
  const __hip_bfloat16* bP0 = B0 + (size_t)(n0 + c0r) * K + (cs ^ (c0r & 7)) * 8;
  const __hip_bfloat16* bP1 = B0 + (size_t)(n0 + c1r) * K + (cs ^ (c1r & 7)) * 8;
  const size_t HK = (size_t)128 * K;

#define STAGE_T(bb, koff)                                                    \
  do {                                                                       \
    GLDS16(aP0 + (koff), (char*)As[bb] + t * 16);                            \
    GLDS16(aP1 + (koff), (char*)As[bb] + 8192 + t * 16);                     \
    GLDS16(bP0 + (koff), (char*)Bs[bb] + t * 16);                            \
    GLDS16(bP1 + (koff), (char*)Bs[bb] + 8192 + t * 16);                     \
    GLDS16(bP0 + HK + (koff), (char*)Bs[bb] + 16384 + t * 16);               \
    GLDS16(bP1 + HK + (koff), (char*)Bs[bb] + 24576 + t * 16);               \
  } while (0)

  f32x4 acc[2][4][2] = {};
  bf16x8 afA[4][2];
  bf16x8 bqA[2][2], bqB[2][2];
  const int NT = K / 64;
  const int sw = lr & 7;
  const int arow = (w >> 2) * 64;
  const int brow = (w & 3) * 32;

#define RD_A(dst)                                                            \
  _Pragma("unroll") for (int mi = 0; mi < 4; ++mi)                           \
    _Pragma("unroll") for (int kk = 0; kk < 2; ++kk)                         \
      dst[mi][kk] = *(const bf16x8*)((const char*)As[buf] +                  \
          (arow + mi * 16 + lr) * 128 + (((kk * 4 + hi) ^ sw) << 4));
#define RD_B(dst, nh)                                                        \
  _Pragma("unroll") for (int ni = 0; ni < 2; ++ni)                           \
    _Pragma("unroll") for (int kk = 0; kk < 2; ++kk)                         \
      dst[ni][kk] = *(const bf16x8*)((const char*)Bs[buf] +                  \
          ((nh) * 128 + brow + ni * 16 + lr) * 128 + (((kk * 4 + hi) ^ sw) << 4));
#define MFMA_Q(nh, afv, bq)                                                  \
  do {                                                                       \
    __builtin_amdgcn_s_setprio(1);                                           \
    _Pragma("unroll") for (int mi = 0; mi < 4; ++mi)                         \
      _Pragma("unroll") for (int ni = 0; ni < 2; ++ni) {                     \
        acc[nh][mi][ni] = __builtin_amdgcn_mfma_f32_16x16x32_bf16(           \
            afv[mi][0], bq[ni][0], acc[nh][mi][ni], 0, 0, 0);                \
        acc[nh][mi][ni] = __builtin_amdgcn_mfma_f32_16x16x32_bf16(           \
            afv[mi][1], bq[ni][1], acc[nh][mi][ni], 0, 0, 0);                \
      }                                                                      \
    __builtin_amdgcn_s_setprio(0);                                           \
  } while (0)
#define WAITV(n)  asm volatile("s_waitcnt vmcnt(" #n ")" ::: "memory")

  STAGE_T(0, 0);

  for (int tt = 0; tt < NT; ++tt) {
    const int buf = tt & 1, nb = buf ^ 1;
    const bool stg = (tt + 1 < NT);
    const size_t ko = (size_t)(tt + 1) * 64;

    WAITV(0);
    __builtin_amdgcn_s_barrier();
    RD_A(afA);
    RD_B(bqA, 0);
    RD_B(bqB, 1);
    if (stg) STAGE_T(nb, ko);
    MFMA_Q(0, afA, bqA);
    MFMA_Q(1, afA, bqB);
  }
#undef WAITV
#undef MFMA_Q
#undef RD_B
#undef RD_A
#undef STAGE_T

#pragma unroll
  for (int nh = 0; nh < 2; ++nh)
#pragma unroll
    for (int mi = 0; mi < 4; ++mi)
#pragma unroll
      for (int ni = 0; ni < 2; ++ni)
#pragma unroll
        for (int i = 0; i < 4; ++i) {
          size_t idx = (size_t)(m0 + arow + mi * 16 + hi * 4 + i) * N +
                       (n0 + nh * 128 + brow + ni * 16 + lr);
          store1(&C0[idx], acc[nh][mi][ni][i]);
        }
}

// ---------------- flash attention v4 (causal), swapped QK^T (r9 proven version) ----------------
__global__ __launch_bounds__(256, 2) void flash_attn(const __hip_bfloat16* __restrict__ Qg,
                                                     const __hip_bfloat16* __restrict__ Kg,
                                                     const __hip_bfloat16* __restrict__ Vg,
                                                     __hip_bfloat16* __restrict__ Og) {
  __shared__ __hip_bfloat16 Ks[2][64 * 128];  // [k][d], slot ^= (k&7) via source pre-swizzle
  __shared__ __hip_bfloat16 Vt[128 * 64];     // [d][k], slot ^= ((d>>3)^d)&7

  const int mblk = blockIdx.x;
  const int bh = mblk & 31;
  const int jj = mblk >> 5;                        // heavy q-tiles dispatch first
  const int qt = (jj < 8) ? (15 - jj) : (jj - 8);  // pair (c, c+256) sums to 34 tiles
  const int b = bh >> 4, h = bh & 15;
  const int q0 = qt * 128;
  const int t = threadIdx.x, w = t >> 6, l = t & 63;
  const int lr = l & 15, hi = l >> 4;
  const size_t base = ((size_t)b * 2048) * 2048 + (size_t)h * 128;
  const int nt = 2 * qt + 2;
  const float scale = 0.08838834764831843f;  // 1/sqrt(128)

  const int hi2 = (hi & 1) * 2;
  const int addrA = (((hi2) << 4) | lr) << 2;
  const int addrB = (((hi2 + 1) << 4) | lr) << 2;
  int addr_o[4];
#pragma unroll
  for (int i = 0; i < 4; ++i) addr_o[i] = ((l & 48) | (hi * 4 + i)) << 2;
  const bool hiHigh = (hi >> 1) != 0;

  bf16x8 qf[2][4];
#pragma unroll
  for (int g = 0; g < 2; ++g) {
    const __hip_bfloat16* qrow = Qg + base + (size_t)(q0 + w * 32 + g * 16 + lr) * 2048;
#pragma unroll
    for (int kk = 0; kk < 4; ++kk)
      qf[g][kk] = *(const bf16x8*)(qrow + kk * 32 + hi * 8);
  }

  f32x4 o_acc[2][8] = {};
  float m_run[2] = {-1e30f, -1e30f};
  float l_run[2] = {0.f, 0.f};

  const __hip_bfloat16* kptr[4];
#pragma unroll
  for (int i = 0; i < 4; ++i) {
    int c = i * 256 + t;
    int kr = c >> 4;
    int ke = ((c & 15) ^ (kr & 7)) * 8;
    kptr[i] = Kg + base + (size_t)kr * 2048 + ke;
  }
  const __hip_bfloat16* vptr[2];
#pragma unroll
  for (int it = 0; it < 2; ++it) {
    int kp = it * 16 + w * 4 + hi;
    vptr[it] = Vg + base + (size_t)(kp * 2) * 2048 + lr * 8;
  }

  u16x8 va[2], vb[2];
#pragma unroll
  for (int i = 0; i < 4; ++i)
    GLDS16(kptr[i], (char*)Ks[0] + (i * 256 + t) * 16);
#pragma unroll
  for (int it = 0; it < 2; ++it) {
    va[it] = *(const u16x8*)vptr[it];
    vb[it] = *(const u16x8*)(vptr[it] + 2048);
  }

  for (int kt = 0; kt < nt; ++kt) {
    const int cur = kt & 1;
    const int kb = kt * 64;
    __syncthreads();

#pragma unroll
    for (int it = 0; it < 2; ++it)
#pragma unroll
      for (int j2 = 0; j2 < 8; ++j2) {
        int d = lr * 8 + j2;
        int sw = (lr ^ j2) & 7;
        int off = d * 128 + (((it * 4 + w) ^ sw) << 4) + hi * 4;
        *(unsigned int*)((char*)Vt + off) =
            (unsigned int)va[it][j2] | ((unsigned int)vb[it][j2] << 16);
      }
    if (kt + 1 < nt) {
      const size_t adv = (size_t)(kb + 64) * 2048;
#pragma unroll
      for (int i = 0; i < 4; ++i)
        GLDS16(kptr[i] + adv, (char*)Ks[cur ^ 1] + (i * 256 + t) * 16);
#pragma unroll
      for (int it = 0; it < 2; ++it) {
        va[it] = *(const u16x8*)(vptr[it] + adv);
        vb[it] = *(const u16x8*)(vptr[it] + adv + 2048);
      }
    }
    asm volatile("s_waitcnt lgkmcnt(0)" ::: "memory");
    __builtin_amdgcn_s_barrier();

    if (!(kt == nt - 1 && w < 2)) {
      const char* ks = (const char*)Ks[cur];

      f32x4 st[2][4];
#pragma unroll
      for (int g = 0; g < 2; ++g)
#pragma unroll
        for (int nk = 0; nk < 4; ++nk) { f32x4 z = {}; st[g][nk] = z; }
#pragma unroll
      for (int nk = 0; nk < 4; ++nk)
#pragma unroll
        for (int kk = 0; kk < 4; ++kk) {
          bf16x8 kf = *(const bf16x8*)(ks + (nk * 16 + lr) * 256 +
                                       (((kk * 4 + hi) ^ (lr & 7)) << 4));
#pragma unroll
          for (int g = 0; g < 2; ++g)
            st[g][nk] = __builtin_amdgcn_mfma_f32_16x16x32_bf16(kf, qf[g][kk], st[g][nk], 0, 0, 0);
        }

      const bool maskt = (kt >= nt - 2);
#pragma unroll
      for (int g = 0; g < 2; ++g)
#pragma unroll
        for (int nk = 0; nk < 4; ++nk)
#pragma unroll
          for (int i = 0; i < 4; ++i) {
            float v = st[g][nk][i] * scale;
            if (maskt) {
              int ki = kb + nk * 16 + hi * 4 + i;
              int qi = q0 + w * 32 + g * 16 + lr;
              if (ki > qi) v = -1e30f;
            }
            st[g][nk][i] = v;
          }

      bf16x8 paf[2][2];
#pragma unroll
      for (int g = 0; g < 2; ++g) {
        float t0 = fmaxf(fmaxf(st[g][0][0], st[g][0][1]), fmaxf(st[g][0][2], st[g][0][3]));
        float t1 = fmaxf(fmaxf(st[g][1][0], st[g][1][1]), fmaxf(st[g][1][2], st[g][1][3]));
        float t2 = fmaxf(fmaxf(st[g][2][0], st[g][2][1]), fmaxf(st[g][2][2], st[g][2][3]));
        float t3 = fmaxf(fmaxf(st[g][3][0], st[g][3][1]), fmaxf(st[g][3][2], st[g][3][3]));
        float mx = fmaxf(fmaxf(t0, t1), fmaxf(t2, t3));
        mx = fmaxf(mx, __shfl_xor(mx, 16));
        mx = fmaxf(mx, __shfl_xor(mx, 32));

        if (!__all(mx - m_run[g] <= 8.0f)) {
          float mnew = fmaxf(m_run[g], mx);
          float rs = __expf(m_run[g] - mnew);
          m_run[g] = mnew;
          l_run[g] *= rs;
          int rsi = __float_as_int(rs);
#pragma unroll
          for (int i = 0; i < 4; ++i) {
            float rso = __int_as_float(__builtin_amdgcn_ds_bpermute(addr_o[i], rsi));
#pragma unroll
            for (int nc = 0; nc < 8; ++nc) o_acc[g][nc][i] *= rso;
          }
        }

#pragma unroll
        for (int nk = 0; nk < 4; ++nk)
#pragma unroll
          for (int i = 0; i < 4; ++i)
            st[g][nk][i] = __expf(st[g][nk][i] - m_run[g]);

        float s0 = (st[g][0][0] + st[g][0][1]) + (st[g][0][2] + st[g][0][3]);
        float s1 = (st[g][1][0] + st[g][1][1]) + (st[g][1][2] + st[g][1][3]);
        float s2 = (st[g][2][0] + st[g][2][1]) + (st[g][2][2] + st[g][2][3]);
        float s3 = (st[g][3][0] + st[g][3][1]) + (st[g][3][2] + st[g][3][3]);
        float sm = (s0 + s1) + (s2 + s3);
        sm += __shfl_xor(sm, 16);
        sm += __shfl_xor(sm, 32);
        l_run[g] += sm;

        unsigned pk[4][2];
#pragma unroll
        for (int nk = 0; nk < 4; ++nk) {
          asm("v_cvt_pk_bf16_f32 %0, %1, %2"
              : "=v"(pk[nk][0]) : "v"(st[g][nk][0]), "v"(st[g][nk][1]));
          asm("v_cvt_pk_bf16_f32 %0, %1, %2"
              : "=v"(pk[nk][1]) : "v"(st[g][nk][2]), "v"(st[g][nk][3]));
        }

#pragma unroll
        for (int kk = 0; kk < 2; ++kk) {
          unsigned au[4];
#pragma unroll
          for (int p = 0; p < 4; ++p) {
            int ad = (p < 2) ? addrA : addrB;
            int v0 = __builtin_amdgcn_ds_bpermute(ad, (int)pk[2 * kk][p & 1]);
            int v1 = __builtin_amdgcn_ds_bpermute(ad, (int)pk[2 * kk + 1][p & 1]);
            au[p] = hiHigh ? (unsigned)v1 : (unsigned)v0;
          }
          union { unsigned u[4]; bf16x8 v; } cv;
          cv.u[0] = au[0]; cv.u[1] = au[1]; cv.u[2] = au[2]; cv.u[3] = au[3];
          paf[g][kk] = cv.v;
        }
      }

#pragma unroll
      for (int kk = 0; kk < 2; ++kk)
#pragma unroll
        for (int nc = 0; nc < 8; ++nc) {
          int d = nc * 16 + lr;
          int sw = ((d >> 3) ^ d) & 7;
          bf16x8 vfr = *(const bf16x8*)((const char*)Vt + d * 128 +
                                        (((kk * 4 + hi) ^ sw) << 4));
#pragma unroll
          for (int g = 0; g < 2; ++g)
            o_acc[g][nc] = __builtin_amdgcn_mfma_f32_16x16x32_bf16(paf[g][kk], vfr, o_acc[g][nc], 0, 0, 0);
        }
    }
  }

#pragma unroll
  for (int g = 0; g < 2; ++g) {
    float lo[4];
#pragma unroll
    for (int i = 0; i < 4; ++i)
      lo[i] = __int_as_float(__builtin_amdgcn_ds_bpermute(addr_o[i], __float_as_int(l_run[g])));
#pragma unroll
    for (int nc = 0; nc < 8; ++nc)
#pragma unroll
      for (int i = 0; i < 4; ++i) {
        float val = o_acc[g][nc][i] / lo[i];
        Og[base + (size_t)(q0 + w * 32 + g * 16 + hi * 4 + i) * 2048 + nc * 16 + lr] =
            __float2bfloat16(val);
      }
  }
}

// ---------------- launch ----------------
extern "C" void kernel_launch(void* const* d_in, const int* in_sizes, int n_in,
                              void* d_out, int out_size, void* d_ws, size_t ws_size,
                              hipStream_t stream) {
  const float* x  = (const float*)d_in[0];
  const float* wq = (const float*)d_in[1];
  const float* wk = (const float*)d_in[2];
  const float* wv = (const float*)d_in[3];
  const float* wo = (const float*)d_in[4];
  float* out = (float*)d_out;

  const int BT = 4096, D = 2048;
  const size_t ND = (size_t)D * D;
  const size_t NX = (size_t)BT * D;

  __hip_bfloat16* xb  = (__hip_bfloat16*)d_ws;
  __hip_bfloat16* wqb = xb + NX;
  __hip_bfloat16* wkb = wqb + ND;
  __hip_bfloat16* wvb = wkb + ND;
  __hip_bfloat16* wob = wvb + ND;
  __hip_bfloat16* Qb  = wob + ND;
  __hip_bfloat16* Kb  = Qb + NX;
  __hip_bfloat16* Vb  = Kb + NX;
  __hip_bfloat16* Ab  = Vb + NX;

  cast_f32_to_bf16<<<(int)(NX / 4 / 256), 256, 0, stream>>>((const float4*)x, (ushort4*)xb, (int)(NX / 4));
  cast4_f32_to_bf16<<<dim3((int)(ND / 4 / 256), 4), 256, 0, stream>>>(
      (const float4*)wq, (const float4*)wk, (const float4*)wv, (const float4*)wo,
      (ushort4*)wqb, (ushort4*)wkb, (ushort4*)wvb, (ushort4*)wob, (int)(ND / 4));

  // fused QKV: 24 N-tiles x 32 M-tiles = 768 blocks (3 blocks/CU resident)
  gemm_qkv<<<768, 512, 0, stream>>>(
      xb, wqb, wkb, wvb, Qb, Kb, Vb, 24, 32, 8, D, D);

  flash_attn<<<512, 256, 0, stream>>>(Qb, Kb, Vb, Ab);

  // output projection: BK=64 single-phase, 256 blocks (1 round, warm data)
  gemm_op<float><<<256, 512, 0, stream>>>(Ab, wob, out, 8, 32, D, D);
}

// Round 20
// 269.506 us; speedup vs baseline: 1.0161x; 1.0161x over previous
//
#include <hip/hip_runtime.h>
#include <hip/hip_bf16.h>

typedef __bf16 bf16x8 __attribute__((ext_vector_type(8)));
typedef float f32x4 __attribute__((ext_vector_type(4)));
typedef unsigned short u16x8 __attribute__((ext_vector_type(8)));

#define GLDS16(g, s)                                                         \
  __builtin_amdgcn_global_load_lds(                                          \
      (const __attribute__((address_space(1))) void*)(g),                    \
      (__attribute__((address_space(3))) void*)(s), 16, 0, 0)

__device__ __forceinline__ void store1(__hip_bfloat16* p, float v) { *p = __float2bfloat16(v); }
__device__ __forceinline__ void store1(float* p, float v) { *p = v; }

// ---------------- cast fp32 -> bf16 ----------------
__global__ __launch_bounds__(256) void cast_f32_to_bf16(const float4* __restrict__ in,
                                                        ushort4* __restrict__ out, int n4) {
  int i = blockIdx.x * 256 + threadIdx.x;
  if (i >= n4) return;
  float4 v = in[i];
  union { ushort4 u; __hip_bfloat16 h[4]; } o;
  o.h[0] = __float2bfloat16(v.x);
  o.h[1] = __float2bfloat16(v.y);
  o.h[2] = __float2bfloat16(v.z);
  o.h[3] = __float2bfloat16(v.w);
  out[i] = o.u;
}

// merged 4-weight cast (blockIdx.y selects matrix)
__global__ __launch_bounds__(256) void cast4_f32_to_bf16(const float4* __restrict__ w0,
                                                         const float4* __restrict__ w1,
                                                         const float4* __restrict__ w2,
                                                         const float4* __restrict__ w3,
                                                         ushort4* __restrict__ o0,
                                                         ushort4* __restrict__ o1,
                                                         ushort4* __restrict__ o2,
                                                         ushort4* __restrict__ o3, int n4) {
  int i = blockIdx.x * 256 + threadIdx.x;
  if (i >= n4) return;
  int s = blockIdx.y;
  const float4* in = (s == 0) ? w0 : (s == 1) ? w1 : (s == 2) ? w2 : w3;
  ushort4* out = (s == 0) ? o0 : (s == 1) ? o1 : (s == 2) ? o2 : o3;
  float4 v = in[i];
  union { ushort4 u; __hip_bfloat16 h[4]; } o;
  o.h[0] = __float2bfloat16(v.x);
  o.h[1] = __float2bfloat16(v.y);
  o.h[2] = __float2bfloat16(v.z);
  o.h[3] = __float2bfloat16(v.w);
  out[i] = o.u;
}

// ------- QKV GEMM: 128x256, BK=32, triple-buf 72 KB, 2 blocks/CU (r17/r18 best) -------
__global__ __launch_bounds__(512, 2) void gemm_qkv(const __hip_bfloat16* __restrict__ A,
                                                   const __hip_bfloat16* __restrict__ B0,
                                                   const __hip_bfloat16* __restrict__ B1,
                                                   const __hip_bfloat16* __restrict__ B2,
                                                   __hip_bfloat16* __restrict__ C0,
                                                   __hip_bfloat16* __restrict__ C1,
                                                   __hip_bfloat16* __restrict__ C2,
                                                   int nBx, int nBy, int ntPerMat,
                                                   int N, int K) {
  __shared__ __hip_bfloat16 As[3][128 * 32];  // 8 KB each
  __shared__ __hip_bfloat16 Bs[3][256 * 32];  // 16 KB each

  const int t = threadIdx.x;
  const int w = t >> 6, l = t & 63;
  const int lr = l & 15, hi = l >> 4;

  const int nwg = nBx * nBy;
  int id = (int)blockIdx.x;
  id = (id & 7) * (nwg >> 3) + (id >> 3);
  const int bx = id / nBy;
  const int by = id % nBy;

  const int sel = bx / ntPerMat;
  const __hip_bfloat16* Bm = (sel == 0) ? B0 : ((sel == 1) ? B1 : B2);
  __hip_bfloat16* Cm = (sel == 0) ? C0 : ((sel == 1) ? C1 : C2);
  const int n0 = (bx - sel * ntPerMat) * 256;
  const int m0 = by * 128;

  const int ar = t >> 2, as_ = t & 3;
  const int swsrc = (as_ ^ ((ar >> 1) & 3)) * 8;
  const __hip_bfloat16* aP  = A  + (size_t)(m0 + ar) * K + swsrc;
  const __hip_bfloat16* bPa = Bm + (size_t)(n0 + ar) * K + swsrc;
  const __hip_bfloat16* bPb = Bm + (size_t)(n0 + 128 + ar) * K + swsrc;

#define STAGE_T(bb, koff)                                                    \
  do {                                                                       \
    GLDS16(aP + (koff), (char*)As[bb] + t * 16);                             \
    GLDS16(bPa + (koff), (char*)Bs[bb] + t * 16);                            \
    GLDS16(bPb + (koff), (char*)Bs[bb] + 8192 + t * 16);                     \
  } while (0)

  f32x4 acc[2][4][2] = {};
  bf16x8 af[4];
  bf16x8 bq[2][2];
  const int NT = K / 32;
  const int swr = (lr >> 1) & 3;
  const int arow = (w >> 2) * 64;
  const int brow = (w & 3) * 32;

#define WAITV(n)  asm volatile("s_waitcnt vmcnt(" #n ")" ::: "memory")

  STAGE_T(0, 0);
  STAGE_T(1, 32);

  for (int tt = 0; tt < NT; ++tt) {
    const int buf = tt % 3;

    if (tt + 1 < NT) WAITV(3); else WAITV(0);
    __builtin_amdgcn_s_barrier();

#pragma unroll
    for (int mi = 0; mi < 4; ++mi)
      af[mi] = *(const bf16x8*)((const char*)As[buf] +
          (arow + mi * 16 + lr) * 64 + ((hi ^ swr) << 4));
#pragma unroll
    for (int nh = 0; nh < 2; ++nh)
#pragma unroll
      for (int ni = 0; ni < 2; ++ni)
        bq[nh][ni] = *(const bf16x8*)((const char*)Bs[buf] +
            (nh * 128 + brow + ni * 16 + lr) * 64 + ((hi ^ swr) << 4));

    if (tt + 2 < NT) STAGE_T((tt + 2) % 3, (size_t)(tt + 2) * 32);

    __builtin_amdgcn_s_setprio(1);
#pragma unroll
    for (int nh = 0; nh < 2; ++nh)
#pragma unroll
      for (int mi = 0; mi < 4; ++mi)
#pragma unroll
        for (int ni = 0; ni < 2; ++ni)
          acc[nh][mi][ni] = __builtin_amdgcn_mfma_f32_16x16x32_bf16(
              af[mi], bq[nh][ni], acc[nh][mi][ni], 0, 0, 0);
    __builtin_amdgcn_s_setprio(0);
  }
#undef WAITV
#undef STAGE_T

#pragma unroll
  for (int nh = 0; nh < 2; ++nh)
#pragma unroll
    for (int mi = 0; mi < 4; ++mi)
#pragma unroll
      for (int ni = 0; ni < 2; ++ni)
#pragma unroll
        for (int i = 0; i < 4; ++i) {
          size_t idx = (size_t)(m0 + arow + mi * 16 + hi * 4 + i) * N +
                       (n0 + nh * 128 + brow + ni * 16 + lr);
          store1(&Cm[idx], acc[nh][mi][ni][i]);
        }
}

// ------- out-proj GEMM: 128x256, BK=64, dbuf single-phase (r15 best: ~19us warm) -------
template <typename OutT>
__global__ __launch_bounds__(512, 2) void gemm_op(const __hip_bfloat16* __restrict__ A,
                                                  const __hip_bfloat16* __restrict__ B0,
                                                  OutT* __restrict__ C0,
                                                  int nBx, int nBy, int N, int K) {
  __shared__ __hip_bfloat16 As[2][128 * 64];  // 16 KB per buf
  __shared__ __hip_bfloat16 Bs[2][256 * 64];  // 32 KB per buf

  const int t = threadIdx.x;
  const int w = t >> 6, l = t & 63;
  const int lr = l & 15, hi = l >> 4;

  const int nwg = nBx * nBy;
  int id = (int)blockIdx.x;
  id = (id & 7) * (nwg >> 3) + (id >> 3);
  const int bx = id / nBy;
  const int by = id % nBy;

  const int n0 = bx * 256;
  const int m0 = by * 128;

  const int c0r = t >> 3, cs = t & 7;
  const int c1r = 64 + c0r;
  const __hip_bfloat16* aP0 = A + (size_t)(m0 + c0r) * K + (cs ^ (c0r & 7)) * 8;
  const __hip_bfloat16* aP1 = A + (size_t)(m0 + c1r) * K + (cs ^ (c1r & 7)) * 8;
  const __hip_bfloat16* bP0 = B0 + (size_t)(n0 + c0r) * K + (cs ^ (c0r & 7)) * 8;
  const __hip_bfloat16* bP1 = B0 + (size_t)(n0 + c1r) * K + (cs ^ (c1r & 7)) * 8;
  const size_t HK = (size_t)128 * K;

#define STAGE_T(bb, koff)                                                    \
  do {                                                                       \
    GLDS16(aP0 + (koff), (char*)As[bb] + t * 16);                            \
    GLDS16(aP1 + (koff), (char*)As[bb] + 8192 + t * 16);                     \
    GLDS16(bP0 + (koff), (char*)Bs[bb] + t * 16);                            \
    GLDS16(bP1 + (koff), (char*)Bs[bb] + 8192 + t * 16);                     \
    GLDS16(bP0 + HK + (koff), (char*)Bs[bb] + 16384 + t * 16);               \
    GLDS16(bP1 + HK + (koff), (char*)Bs[bb] + 24576 + t * 16);               \
  } while (0)

  f32x4 acc[2][4][2] = {};
  bf16x8 afA[4][2];
  bf16x8 bqA[2][2], bqB[2][2];
  const int NT = K / 64;
  const int sw = lr & 7;
  const int arow = (w >> 2) * 64;
  const int brow = (w & 3) * 32;

#define RD_A(dst)                                                            \
  _Pragma("unroll") for (int mi = 0; mi < 4; ++mi)                           \
    _Pragma("unroll") for (int kk = 0; kk < 2; ++kk)                         \
      dst[mi][kk] = *(const bf16x8*)((const char*)As[buf] +                  \
          (arow + mi * 16 + lr) * 128 + (((kk * 4 + hi) ^ sw) << 4));
#define RD_B(dst, nh)                                                        \
  _Pragma("unroll") for (int ni = 0; ni < 2; ++ni)                           \
    _Pragma("unroll") for (int kk = 0; kk < 2; ++kk)                         \
      dst[ni][kk] = *(const bf16x8*)((const char*)Bs[buf] +                  \
          ((nh) * 128 + brow + ni * 16 + lr) * 128 + (((kk * 4 + hi) ^ sw) << 4));
#define MFMA_Q(nh, afv, bq)                                                  \
  do {                                                                       \
    __builtin_amdgcn_s_setprio(1);                                           \
    _Pragma("unroll") for (int mi = 0; mi < 4; ++mi)                         \
      _Pragma("unroll") for (int ni = 0; ni < 2; ++ni) {                     \
        acc[nh][mi][ni] = __builtin_amdgcn_mfma_f32_16x16x32_bf16(           \
            afv[mi][0], bq[ni][0], acc[nh][mi][ni], 0, 0, 0);                \
        acc[nh][mi][ni] = __builtin_amdgcn_mfma_f32_16x16x32_bf16(           \
            afv[mi][1], bq[ni][1], acc[nh][mi][ni], 0, 0, 0);                \
      }                                                                      \
    __builtin_amdgcn_s_setprio(0);                                           \
  } while (0)
#define WAITV(n)  asm volatile("s_waitcnt vmcnt(" #n ")" ::: "memory")

  STAGE_T(0, 0);

  for (int tt = 0; tt < NT; ++tt) {
    const int buf = tt & 1, nb = buf ^ 1;
    const bool stg = (tt + 1 < NT);
    const size_t ko = (size_t)(tt + 1) * 64;

    WAITV(0);
    __builtin_amdgcn_s_barrier();
    RD_A(afA);
    RD_B(bqA, 0);
    RD_B(bqB, 1);
    if (stg) STAGE_T(nb, ko);
    MFMA_Q(0, afA, bqA);
    MFMA_Q(1, afA, bqB);
  }
#undef WAITV
#undef MFMA_Q
#undef RD_B
#undef RD_A
#undef STAGE_T

#pragma unroll
  for (int nh = 0; nh < 2; ++nh)
#pragma unroll
    for (int mi = 0; mi < 4; ++mi)
#pragma unroll
      for (int ni = 0; ni < 2; ++ni)
#pragma unroll
        for (int i = 0; i < 4; ++i) {
          size_t idx = (size_t)(m0 + arow + mi * 16 + hi * 4 + i) * N +
                       (n0 + nh * 128 + brow + ni * 16 + lr);
          store1(&C0[idx], acc[nh][mi][ni][i]);
        }
}

// ---------------- flash attention v4 (causal), swapped QK^T (r9 proven version) ----------------
__global__ __launch_bounds__(256, 2) void flash_attn(const __hip_bfloat16* __restrict__ Qg,
                                                     const __hip_bfloat16* __restrict__ Kg,
                                                     const __hip_bfloat16* __restrict__ Vg,
                                                     __hip_bfloat16* __restrict__ Og) {
  __shared__ __hip_bfloat16 Ks[2][64 * 128];  // [k][d], slot ^= (k&7) via source pre-swizzle
  __shared__ __hip_bfloat16 Vt[128 * 64];     // [d][k], slot ^= ((d>>3)^d)&7

  const int mblk = blockIdx.x;
  const int bh = mblk & 31;
  const int jj = mblk >> 5;                        // heavy q-tiles dispatch first
  const int qt = (jj < 8) ? (15 - jj) : (jj - 8);  // pair (c, c+256) sums to 34 tiles
  const int b = bh >> 4, h = bh & 15;
  const int q0 = qt * 128;
  const int t = threadIdx.x, w = t >> 6, l = t & 63;
  const int lr = l & 15, hi = l >> 4;
  const size_t base = ((size_t)b * 2048) * 2048 + (size_t)h * 128;
  const int nt = 2 * qt + 2;
  const float scale = 0.08838834764831843f;  // 1/sqrt(128)

  const int hi2 = (hi & 1) * 2;
  const int addrA = (((hi2) << 4) | lr) << 2;
  const int addrB = (((hi2 + 1) << 4) | lr) << 2;
  int addr_o[4];
#pragma unroll
  for (int i = 0; i < 4; ++i) addr_o[i] = ((l & 48) | (hi * 4 + i)) << 2;
  const bool hiHigh = (hi >> 1) != 0;

  bf16x8 qf[2][4];
#pragma unroll
  for (int g = 0; g < 2; ++g) {
    const __hip_bfloat16* qrow = Qg + base + (size_t)(q0 + w * 32 + g * 16 + lr) * 2048;
#pragma unroll
    for (int kk = 0; kk < 4; ++kk)
      qf[g][kk] = *(const bf16x8*)(qrow + kk * 32 + hi * 8);
  }

  f32x4 o_acc[2][8] = {};
  float m_run[2] = {-1e30f, -1e30f};
  float l_run[2] = {0.f, 0.f};

  const __hip_bfloat16* kptr[4];
#pragma unroll
  for (int i = 0; i < 4; ++i) {
    int c = i * 256 + t;
    int kr = c >> 4;
    int ke = ((c & 15) ^ (kr & 7)) * 8;
    kptr[i] = Kg + base + (size_t)kr * 2048 + ke;
  }
  const __hip_bfloat16* vptr[2];
#pragma unroll
  for (int it = 0; it < 2; ++it) {
    int kp = it * 16 + w * 4 + hi;
    vptr[it] = Vg + base + (size_t)(kp * 2) * 2048 + lr * 8;
  }

  u16x8 va[2], vb[2];
#pragma unroll
  for (int i = 0; i < 4; ++i)
    GLDS16(kptr[i], (char*)Ks[0] + (i * 256 + t) * 16);
#pragma unroll
  for (int it = 0; it < 2; ++it) {
    va[it] = *(const u16x8*)vptr[it];
    vb[it] = *(const u16x8*)(vptr[it] + 2048);
  }

  for (int kt = 0; kt < nt; ++kt) {
    const int cur = kt & 1;
    const int kb = kt * 64;
    __syncthreads();

#pragma unroll
    for (int it = 0; it < 2; ++it)
#pragma unroll
      for (int j2 = 0; j2 < 8; ++j2) {
        int d = lr * 8 + j2;
        int sw = (lr ^ j2) & 7;
        int off = d * 128 + (((it * 4 + w) ^ sw) << 4) + hi * 4;
        *(unsigned int*)((char*)Vt + off) =
            (unsigned int)va[it][j2] | ((unsigned int)vb[it][j2] << 16);
      }
    if (kt + 1 < nt) {
      const size_t adv = (size_t)(kb + 64) * 2048;
#pragma unroll
      for (int i = 0; i < 4; ++i)
        GLDS16(kptr[i] + adv, (char*)Ks[cur ^ 1] + (i * 256 + t) * 16);
#pragma unroll
      for (int it = 0; it < 2; ++it) {
        va[it] = *(const u16x8*)(vptr[it] + adv);
        vb[it] = *(const u16x8*)(vptr[it] + adv + 2048);
      }
    }
    asm volatile("s_waitcnt lgkmcnt(0)" ::: "memory");
    __builtin_amdgcn_s_barrier();

    if (!(kt == nt - 1 && w < 2)) {
      const char* ks = (const char*)Ks[cur];

      f32x4 st[2][4];
#pragma unroll
      for (int g = 0; g < 2; ++g)
#pragma unroll
        for (int nk = 0; nk < 4; ++nk) { f32x4 z = {}; st[g][nk] = z; }
#pragma unroll
      for (int nk = 0; nk < 4; ++nk)
#pragma unroll
        for (int kk = 0; kk < 4; ++kk) {
          bf16x8 kf = *(const bf16x8*)(ks + (nk * 16 + lr) * 256 +
                                       (((kk * 4 + hi) ^ (lr & 7)) << 4));
#pragma unroll
          for (int g = 0; g < 2; ++g)
            st[g][nk] = __builtin_amdgcn_mfma_f32_16x16x32_bf16(kf, qf[g][kk], st[g][nk], 0, 0, 0);
        }

      const bool maskt = (kt >= nt - 2);
#pragma unroll
      for (int g = 0; g < 2; ++g)
#pragma unroll
        for (int nk = 0; nk < 4; ++nk)
#pragma unroll
          for (int i = 0; i < 4; ++i) {
            float v = st[g][nk][i] * scale;
            if (maskt) {
              int ki = kb + nk * 16 + hi * 4 + i;
              int qi = q0 + w * 32 + g * 16 + lr;
              if (ki > qi) v = -1e30f;
            }
            st[g][nk][i] = v;
          }

      bf16x8 paf[2][2];
#pragma unroll
      for (int g = 0; g < 2; ++g) {
        float t0 = fmaxf(fmaxf(st[g][0][0], st[g][0][1]), fmaxf(st[g][0][2], st[g][0][3]));
        float t1 = fmaxf(fmaxf(st[g][1][0], st[g][1][1]), fmaxf(st[g][1][2], st[g][1][3]));
        float t2 = fmaxf(fmaxf(st[g][2][0], st[g][2][1]), fmaxf(st[g][2][2], st[g][2][3]));
        float t3 = fmaxf(fmaxf(st[g][3][0], st[g][3][1]), fmaxf(st[g][3][2], st[g][3][3]));
        float mx = fmaxf(fmaxf(t0, t1), fmaxf(t2, t3));
        mx = fmaxf(mx, __shfl_xor(mx, 16));
        mx = fmaxf(mx, __shfl_xor(mx, 32));

        if (!__all(mx - m_run[g] <= 8.0f)) {
          float mnew = fmaxf(m_run[g], mx);
          float rs = __expf(m_run[g] - mnew);
          m_run[g] = mnew;
          l_run[g] *= rs;
          int rsi = __float_as_int(rs);
#pragma unroll
          for (int i = 0; i < 4; ++i) {
            float rso = __int_as_float(__builtin_amdgcn_ds_bpermute(addr_o[i], rsi));
#pragma unroll
            for (int nc = 0; nc < 8; ++nc) o_acc[g][nc][i] *= rso;
          }
        }

#pragma unroll
        for (int nk = 0; nk < 4; ++nk)
#pragma unroll
          for (int i = 0; i < 4; ++i)
            st[g][nk][i] = __expf(st[g][nk][i] - m_run[g]);

        float s0 = (st[g][0][0] + st[g][0][1]) + (st[g][0][2] + st[g][0][3]);
        float s1 = (st[g][1][0] + st[g][1][1]) + (st[g][1][2] + st[g][1][3]);
        float s2 = (st[g][2][0] + st[g][2][1]) + (st[g][2][2] + st[g][2][3]);
        float s3 = (st[g][3][0] + st[g][3][1]) + (st[g][3][2] + st[g][3][3]);
        float sm = (s0 + s1) + (s2 + s3);
        sm += __shfl_xor(sm, 16);
        sm += __shfl_xor(sm, 32);
        l_run[g] += sm;

        unsigned pk[4][2];
#pragma unroll
        for (int nk = 0; nk < 4; ++nk) {
          asm("v_cvt_pk_bf16_f32 %0, %1, %2"
              : "=v"(pk[nk][0]) : "v"(st[g][nk][0]), "v"(st[g][nk][1]));
          asm("v_cvt_pk_bf16_f32 %0, %1, %2"
              : "=v"(pk[nk][1]) : "v"(st[g][nk][2]), "v"(st[g][nk][3]));
        }

#pragma unroll
        for (int kk = 0; kk < 2; ++kk) {
          unsigned au[4];
#pragma unroll
          for (int p = 0; p < 4; ++p) {
            int ad = (p < 2) ? addrA : addrB;
            int v0 = __builtin_amdgcn_ds_bpermute(ad, (int)pk[2 * kk][p & 1]);
            int v1 = __builtin_amdgcn_ds_bpermute(ad, (int)pk[2 * kk + 1][p & 1]);
            au[p] = hiHigh ? (unsigned)v1 : (unsigned)v0;
          }
          union { unsigned u[4]; bf16x8 v; } cv;
          cv.u[0] = au[0]; cv.u[1] = au[1]; cv.u[2] = au[2]; cv.u[3] = au[3];
          paf[g][kk] = cv.v;
        }
      }

#pragma unroll
      for (int kk = 0; kk < 2; ++kk)
#pragma unroll
        for (int nc = 0; nc < 8; ++nc) {
          int d = nc * 16 + lr;
          int sw = ((d >> 3) ^ d) & 7;
          bf16x8 vfr = *(const bf16x8*)((const char*)Vt + d * 128 +
                                        (((kk * 4 + hi) ^ sw) << 4));
#pragma unroll
          for (int g = 0; g < 2; ++g)
            o_acc[g][nc] = __builtin_amdgcn_mfma_f32_16x16x32_bf16(paf[g][kk], vfr, o_acc[g][nc], 0, 0, 0);
        }
    }
  }

#pragma unroll
  for (int g = 0; g < 2; ++g) {
    float lo[4];
#pragma unroll
    for (int i = 0; i < 4; ++i)
      lo[i] = __int_as_float(__builtin_amdgcn_ds_bpermute(addr_o[i], __float_as_int(l_run[g])));
#pragma unroll
    for (int nc = 0; nc < 8; ++nc)
#pragma unroll
      for (int i = 0; i < 4; ++i) {
        float val = o_acc[g][nc][i] / lo[i];
        Og[base + (size_t)(q0 + w * 32 + g * 16 + hi * 4 + i) * 2048 + nc * 16 + lr] =
            __float2bfloat16(val);
      }
  }
}

// ---------------- launch ----------------
extern "C" void kernel_launch(void* const* d_in, const int* in_sizes, int n_in,
                              void* d_out, int out_size, void* d_ws, size_t ws_size,
                              hipStream_t stream) {
  const float* x  = (const float*)d_in[0];
  const float* wq = (const float*)d_in[1];
  const float* wk = (const float*)d_in[2];
  const float* wv = (const float*)d_in[3];
  const float* wo = (const float*)d_in[4];
  float* out = (float*)d_out;

  const int BT = 4096, D = 2048;
  const size_t ND = (size_t)D * D;
  const size_t NX = (size_t)BT * D;

  __hip_bfloat16* xb  = (__hip_bfloat16*)d_ws;
  __hip_bfloat16* wqb = xb + NX;
  __hip_bfloat16* wkb = wqb + ND;
  __hip_bfloat16* wvb = wkb + ND;
  __hip_bfloat16* wob = wvb + ND;
  __hip_bfloat16* Qb  = wob + ND;
  __hip_bfloat16* Kb  = Qb + NX;
  __hip_bfloat16* Vb  = Kb + NX;
  __hip_bfloat16* Ab  = Vb + NX;

  cast_f32_to_bf16<<<(int)(NX / 4 / 256), 256, 0, stream>>>((const float4*)x, (ushort4*)xb, (int)(NX / 4));
  cast4_f32_to_bf16<<<dim3((int)(ND / 4 / 256), 4), 256, 0, stream>>>(
      (const float4*)wq, (const float4*)wk, (const float4*)wv, (const float4*)wo,
      (ushort4*)wqb, (ushort4*)wkb, (ushort4*)wvb, (ushort4*)wob, (int)(ND / 4));

  // fused QKV: 24 N-tiles x 32 M-tiles = 768 blocks (2 blocks/CU resident)
  gemm_qkv<<<768, 512, 0, stream>>>(
      xb, wqb, wkb, wvb, Qb, Kb, Vb, 24, 32, 8, D, D);

  flash_attn<<<512, 256, 0, stream>>>(Qb, Kb, Vb, Ab);

  // output projection: BK=64 single-phase, 256 blocks (1 round, warm data)
  gemm_op<float><<<256, 512, 0, stream>>>(Ab, wob, out, 8, 32, D, D);
}